// Round 9
// baseline (148.470 us; speedup 1.0000x reference)
//
#include <hip/hip_runtime.h>
#include <math.h>

typedef short v4s __attribute__((ext_vector_type(4)));
typedef short v8s __attribute__((ext_vector_type(8)));
typedef float v4f __attribute__((ext_vector_type(4)));

#define L2E 1.4426950408889634f
#define INV_SCALE 0.08838834764831845f       // 1/sqrt(128)
#define SCL2 (INV_SCALE * L2E)               // folded scale for exp2

static __device__ __forceinline__ short f2bf(float x) {
    union { float f; unsigned u; } c; c.f = x;
    unsigned u = c.u;
    unsigned r = (u + 0x7fffu + ((u >> 16) & 1u)) >> 16;  // RNE
    return (short)r;
}

// ---- P0 fused (verbatim R8, verified): 512 blocks. isel=0: ctx gemm->Qa.
// isel=1: qry gemm->Ka PLUS fused qry transpose->VaT + maskadd. VaT written
// with chunk-XOR swizzle (granule j of row d at position j^(d&7)).
__global__ __launch_bounds__(256) void k_pre(const float* __restrict__ ctx,
                                             const float* __restrict__ qry,
                                             const float* __restrict__ Win,
                                             const float* __restrict__ Wmem,
                                             const int* __restrict__ qmask,
                                             short* __restrict__ Qa,
                                             short* __restrict__ Ka,
                                             short* __restrict__ VaT,
                                             float* __restrict__ maskadd) {
    __shared__ __align__(16) short WtS[128 * 132];      // 33792 B
    __shared__ __align__(16) short Tt[256 * 72];        // 36864 B ([k][row64+pad])
    int x = blockIdx.x;
    int tid = threadIdx.x;
    int msel = x & 255, isel = x >> 8;
    const float* X = isel ? qry : ctx;
    const float* W = isel ? Wmem : Win;
    short* Y = isel ? Ka : Qa;

    int w = tid >> 6, lane = tid & 63;
    int ln = lane & 15, qd = lane >> 4;
    int m0 = msel * 64 + w * 16;
    v4f zero = {0.f, 0.f, 0.f, 0.f};
    v4f o[8];
#pragma unroll
    for (int i = 0; i < 8; ++i) o[i] = zero;

#pragma unroll 1
    for (int kh = 0; kh < 2; ++kh) {
        if (kh) __syncthreads();                        // protect WtS reuse
#pragma unroll 8
        for (int i = 0; i < 64; ++i) {
            int id = i * 256 + tid;
            int k = id >> 7, fp = id & 127;
            WtS[fp * 132 + k] = f2bf(W[(kh * 128 + k) * 128 + fp]);
        }
        __syncthreads();
#pragma unroll
        for (int kk = 0; kk < 4; ++kk) {
            const float* xp = X + (size_t)(m0 + ln) * 256 + kh * 128 + kk * 32 + qd * 8;
            float4 x0 = *(const float4*)xp;
            float4 x1 = *(const float4*)(xp + 4);
            v8s a;
            a[0] = f2bf(x0.x); a[1] = f2bf(x0.y); a[2] = f2bf(x0.z); a[3] = f2bf(x0.w);
            a[4] = f2bf(x1.x); a[5] = f2bf(x1.y); a[6] = f2bf(x1.z); a[7] = f2bf(x1.w);
            if (isel) {                                  // fused transpose staging
#pragma unroll
                for (int si = 0; si < 8; ++si)
                    Tt[(kh * 128 + kk * 32 + qd * 8 + si) * 72 + (w * 16 + ln)] = a[si];
            }
#pragma unroll
            for (int nt = 0; nt < 8; ++nt) {
                v8s bfr = *(const v8s*)(WtS + (nt * 16 + ln) * 132 + kk * 32 + qd * 8);
                o[nt] = __builtin_amdgcn_mfma_f32_16x16x32_bf16(a, bfr, o[nt], 0, 0, 0);
            }
        }
    }
#pragma unroll
    for (int nt = 0; nt < 8; ++nt) {
#pragma unroll
        for (int r = 0; r < 4; ++r) {
            float v = o[nt][r];
            v = v > 0.f ? v : 0.01f * (__expf(v) - 1.f);
            Y[(size_t)(m0 + qd * 4 + r) * 128 + nt * 16 + ln] = f2bf(v);
        }
    }

    if (isel) {
        __syncthreads();                                 // Tt complete
        int b2 = msel >> 5, q0 = (msel & 31) * 64;
        int dr = tid >> 3, j = tid & 7;
#pragma unroll
        for (int i = 0; i < 8; ++i) {
            int d = dr + i * 32;
            v8s vv = *(const v8s*)(Tt + d * 72 + j * 8);
            *(v8s*)(VaT + ((size_t)(b2 * 256 + d)) * 2048 + q0 + ((j ^ (d & 7)) << 3)) = vv;
        }
        if (tid < 64) {
            int qq = b2 * 2048 + q0 + tid;
            maskadd[qq] = (qmask[qq] > 0) ? 0.f : -__builtin_inff();
        }
    }
}

// ------------- flash attention: V-in-registers, 1 barrier/step ------------
// 256 blocks x 512 thr (2 groups of 4 waves; group g owns kv-half). R8's
// V LDS path was a wave-private round-trip (stage+read by the SAME wave) --
// removed: PV's V fragments load DIRECTLY from L2-resident VaT (8 b128/step,
// un-swizzle XOR == pf's XOR; 4 qd-lanes per row cover one full 64B line ->
// fully coalesced). Only cross-wave data is P: PS double-buffered -> ONE
// raw s_barrier + lgkmcnt(0) per step (barrier t+1 is the WAR guard for
// PS[t&1]'s overwrite at t+2). vf loads issued BEFORE the barrier so L2
// latency hides under the barrier convoy. LDS 149.5 -> 70.3 KB.
__global__ __launch_bounds__(512, 2) void k_attn(const short* __restrict__ Qa,
                                                 const short* __restrict__ Ka,
                                                 const short* __restrict__ VaT,
                                                 const float* __restrict__ maskadd,
                                                 float* __restrict__ out) {
    // union: loop uses PSb [grp][buf][64c][64kv] (32 KB); epilogue uses
    // OS [64][260] f32 (66.56 KB); lS at +68224 (2 KB) disjoint from both.
    __shared__ __align__(16) char smem[70272];
    short* PSbase = (short*)smem;
    float* OS = (float*)smem;
    float* lS = (float*)(smem + 68224);

    const int STEPS = 16;
    int blk = blockIdx.x;
    int b = blk & 7;
    int c0 = (blk >> 3) * 64;

    int tid = threadIdx.x;
    int w = tid >> 6, lane = tid & 63, ln = lane & 15, qd = lane >> 4;
    int g = w >> 2, wl = w & 3;              // group (kv half), wave-in-group
    int kv0 = g * 1024;
    short* PSg = PSbase + g * 16384;         // this group's 2 P buffers

    const short* qbase = Qa + (size_t)(b * 2048) * 128;
    const short* kbase = Ka + (size_t)(b * 2048 + kv0 + wl * 16 + ln) * 128 + qd * 8;
    const short* vbase = VaT + (size_t)(b * 256) * 2048;
    const float* mbase = maskadd + b * 2048 + kv0 + wl * 16 + qd * 4;

    // Q fragments for all 4 c-tiles (B-operand layout), resident
    v8s qf[4][4];
#pragma unroll
    for (int ct = 0; ct < 4; ++ct) {
        const short* qp = qbase + (size_t)(c0 + ct * 16 + ln) * 128 + qd * 8;
#pragma unroll
        for (int kk = 0; kk < 4; ++kk) qf[ct][kk] = *(const v8s*)(qp + kk * 32);
    }

    v4f zero = {0.f, 0.f, 0.f, 0.f};
    v4f o[4][4];                            // [ct][dt]; d = wl*64+dt*16+ln
#pragma unroll
    for (int i = 0; i < 4; ++i)
#pragma unroll
        for (int j = 0; j < 4; ++j) o[i][j] = zero;
    float lacc[4] = {0.f, 0.f, 0.f, 0.f};

    // ---- prologue: kf(0)+mask(0) ----
    v8s kfA[4], kfB[4];
    float4 mkA, mkB;
#pragma unroll
    for (int kk = 0; kk < 4; ++kk) kfA[kk] = *(const v8s*)(kbase + kk * 32);
    mkA = *(const float4*)(mbase);

#define ATT_STEP(IT, KFC, MKC, KFN, MKN) do {                                  \
    int q0 = kv0 + (IT) * 64;                                                  \
    int itn = ((IT) + 1) & (STEPS - 1);                                        \
    {   /* prefetch NEXT step's K frags + mask into regs (5 VMEM) */           \
        const short* kp = kbase + (size_t)itn * 8192;                          \
        _Pragma("unroll")                                                      \
        for (int kk = 0; kk < 4; ++kk) KFN[kk] = *(const v8s*)(kp + kk * 32);  \
        MKN = *(const float4*)(mbase + itn * 64);                              \
    }                                                                          \
    short* PSc = PSg + ((IT) & 1) * 8192;                                      \
    int kvb = q0 + wl * 16 + qd * 4;                                           \
    _Pragma("unroll")                                                          \
    for (int ct = 0; ct < 4; ++ct) {                                           \
        v4f s = zero;                                                          \
        _Pragma("unroll")                                                      \
        for (int kk = 0; kk < 4; ++kk)                                         \
            s = __builtin_amdgcn_mfma_f32_16x16x32_bf16(KFC[kk], qf[ct][kk],   \
                                                        s, 0, 0, 0);           \
        int cg = c0 + ct * 16 + ln;                                            \
        v4s pw;                                                                \
        float ls = 0.f;                                                        \
        _Pragma("unroll")                                                      \
        for (int r = 0; r < 4; ++r) {                                          \
            float v = s[r] * SCL2 + (&MKC.x)[r];                               \
            if (kvb + r == cg) v = -__builtin_inff();                          \
            float p = exp2f(v);                                                \
            ls += p;                                                           \
            pw[r] = f2bf(p);                                                   \
        }                                                                      \
        lacc[ct] += ls;                                                        \
        int hs = ((wl * 2 + (qd >> 1)) ^ (ln & 7));                            \
        *(v4s*)(PSc + (ct * 16 + ln) * 64 + hs * 8 + (qd & 1) * 4) = pw;       \
    }                                                                          \
    /* V fragments direct from L2 (issued pre-barrier: latency hides) */       \
    v8s vf2[2][4];                                                             \
    {                                                                          \
        const short* vp = vbase + q0;                                          \
        _Pragma("unroll")                                                      \
        for (int kk2 = 0; kk2 < 2; ++kk2) {                                    \
            int xg = ((kk2 * 4 + qd) ^ (ln & 7)) << 3;                         \
            _Pragma("unroll")                                                  \
            for (int dt = 0; dt < 4; ++dt)                                     \
                vf2[kk2][dt] = *(const v8s*)(vp +                              \
                    (size_t)(wl * 64 + dt * 16 + ln) * 2048 + xg);             \
        }                                                                      \
    }                                                                          \
    asm volatile("s_waitcnt lgkmcnt(0)" ::: "memory");                         \
    __builtin_amdgcn_s_barrier();           /* P visible; WAR for IT-1 buf */  \
    __builtin_amdgcn_s_setprio(1);                                             \
    _Pragma("unroll")                                                          \
    for (int kk2 = 0; kk2 < 2; ++kk2) {                                        \
        v8s pf[4];                                                             \
        _Pragma("unroll")                                                      \
        for (int ct = 0; ct < 4; ++ct)                                         \
            pf[ct] = *(const v8s*)(PSc + (ct * 16 + ln) * 64 +                 \
                                   (((kk2 * 4 + qd) ^ (ln & 7)) << 3));        \
        _Pragma("unroll")                                                      \
        for (int ct = 0; ct < 4; ++ct)                                         \
            _Pragma("unroll")                                                  \
            for (int dt = 0; dt < 4; ++dt)                                     \
                o[ct][dt] = __builtin_amdgcn_mfma_f32_16x16x32_bf16(           \
                    pf[ct], vf2[kk2][dt], o[ct][dt], 0, 0, 0);                 \
    }                                                                          \
    __builtin_amdgcn_s_setprio(0);                                             \
} while (0)

#pragma unroll 1
    for (int it2 = 0; it2 < STEPS; it2 += 2) {
        ATT_STEP(it2, kfA, mkA, kfB, mkB);
        ATT_STEP(it2 + 1, kfB, mkB, kfA, mkA);
    }
#undef ATT_STEP

    // ---- epilogue: combine the two kv-halves ----
    __syncthreads();                         // last PS reads done everywhere

    // l: reduce over qd in-wave, publish per-wave sums (lS disjoint from OS)
#pragma unroll
    for (int ct = 0; ct < 4; ++ct) {
        float v = lacc[ct];
        v += __shfl_xor(v, 16);
        v += __shfl_xor(v, 32);
        if (qd == 0) lS[w * 64 + ct * 16 + ln] = v;
    }

    // group 1 dumps unnormalized O into LDS ([64 c][260 d-pad] f32)
    if (g == 1) {
#pragma unroll
        for (int ct = 0; ct < 4; ++ct)
#pragma unroll
            for (int r = 0; r < 4; ++r)
#pragma unroll
                for (int dt = 0; dt < 4; ++dt)
                    OS[(ct * 16 + qd * 4 + r) * 260 + wl * 64 + dt * 16 + ln] =
                        o[ct][dt][r];
    }
    __syncthreads();

    if (g == 0) {
#pragma unroll
        for (int ct = 0; ct < 4; ++ct) {
            float lv[4];
#pragma unroll
            for (int r = 0; r < 4; ++r) {
                float s = 0.f;
#pragma unroll
                for (int wv = 0; wv < 8; ++wv)
                    s += lS[wv * 64 + ct * 16 + qd * 4 + r];
                lv[r] = s;
            }
            int rowg = b * 2048 + c0 + ct * 16 + qd * 4;
#pragma unroll
            for (int r = 0; r < 4; ++r) {
                float inv = 1.f / lv[r];
#pragma unroll
                for (int dt = 0; dt < 4; ++dt) {
                    int col = wl * 64 + dt * 16 + ln;
                    float sum = o[ct][dt][r] +
                                OS[(ct * 16 + qd * 4 + r) * 260 + col];
                    out[(size_t)(rowg + r) * 256 + col] = sum * inv;
                }
            }
        }
    }
}

extern "C" void kernel_launch(void* const* d_in, const int* in_sizes, int n_in,
                              void* d_out, int out_size, void* d_ws, size_t ws_size,
                              hipStream_t stream) {
    const float* ctx  = (const float*)d_in[0];
    const float* qry  = (const float*)d_in[1];
    const float* win  = (const float*)d_in[2];
    const float* wmem = (const float*)d_in[3];
    const int* qmask  = (const int*)d_in[4];
    float* out = (float*)d_out;

    char* ws = (char*)d_ws;
    short* Qa      = (short*)(ws);                          // 4 MB
    short* Ka      = (short*)(ws + (4u << 20));             // 4 MB
    short* VaT     = (short*)(ws + (8u << 20));             // 8 MB (chunk-XOR swizzled)
    float* maskadd = (float*)(ws + (16u << 20));            // 64 KB

    k_pre<<<dim3(512), 256, 0, stream>>>(ctx, qry, win, wmem, qmask,
                                         Qa, Ka, VaT, maskadd);
    k_attn<<<dim3(256), 512, 0, stream>>>(Qa, Ka, VaT, maskadd, out);
}